// Round 18
// baseline (214.483 us; speedup 1.0000x reference)
//
#include <hip/hip_runtime.h>

#define L_SEQ 8192
#define NTH 512
#define HID 256
#define PIDX(i) ((i) + ((i) >> 4))
#define LDS_SZ 8704        // PIDX(8191)=8702 -> 69632 B per buffer

#define ANG16 3.83495196971410315e-4f   // 2*pi/16384
#define CS16 0.99999992646571789f       // cos(2*pi/16384)
#define SN16 3.83495187571395563e-4f    // sin(2*pi/16384)
#define C707 0.70710678118654752f

// Twiddle table (R14, verified): TWID[off(M)+i2*7+j-1] = exp(-2pi*i*i2*j/(8M))
__device__ float2 TWID[4088];
template<int M> struct TWOFF;
template<> struct TWOFF<512> { static constexpr int v = 0;    };
template<> struct TWOFF<64>  { static constexpr int v = 3584; };
template<> struct TWOFF<8>   { static constexpr int v = 4032; };

// Wide: one entry per thread (R17's 1-block version serialized the GPU ~10us)
__global__ __launch_bounds__(256) void twid_kernel() {
  int g = blockIdx.x * 256 + threadIdx.x;
  float denom;
  int h;
  if (g < 3584)      { h = g;        denom = 4096.0f; }
  else if (g < 4032) { h = g - 3584; denom = 512.0f;  }
  else if (g < 4088) { h = g - 4032; denom = 64.0f;   }
  else return;
  int i = h / 7, j = h - 7*i + 1;
  float s, c;
  sincosf(-6.2831853071795864769f * (float)(i*j) / denom, &s, &c);
  TWID[g] = make_float2(c, s);
}

__device__ __forceinline__ float2 cmul(float2 a, float2 b) {
  return make_float2(a.x*b.x - a.y*b.y, a.x*b.y + a.y*b.x);
}
__device__ __forceinline__ float2 cadd(float2 a, float2 b){ return make_float2(a.x+b.x, a.y+b.y); }
__device__ __forceinline__ float2 csub(float2 a, float2 b){ return make_float2(a.x-b.x, a.y-b.y); }

__device__ __forceinline__ void bf4_fwd(float2 a0, float2 a1, float2 a2, float2 a3,
                                        float2& o0, float2& o1, float2& o2, float2& o3) {
  float2 t0 = cadd(a0,a2), t1 = csub(a0,a2), t2 = cadd(a1,a3), t3 = csub(a1,a3);
  o0 = cadd(t0,t2);
  o2 = csub(t0,t2);
  o1 = make_float2(t1.x + t3.y, t1.y - t3.x);   // t1 - i*t3
  o3 = make_float2(t1.x - t3.y, t1.y + t3.x);   // t1 + i*t3
}
__device__ __forceinline__ void bf4_inv(float2 c0, float2 c1, float2 c2, float2 c3,
                                        float2& o0, float2& o1, float2& o2, float2& o3) {
  float2 u0 = cadd(c0,c2), u2 = csub(c0,c2), u1 = cadd(c1,c3);
  float2 v3 = make_float2(c3.y - c1.y, c1.x - c3.x);  // i*(c1-c3)
  o0 = cadd(u0,u1); o2 = csub(u0,u1); o1 = cadd(u2,v3); o3 = csub(u2,v3);
}

// 8-point DIF DFT in registers, natural output order (verified R7-R17)
__device__ __forceinline__ void fwd8(float2 P[8]) {
  float2 e0=cadd(P[0],P[4]), e1=cadd(P[1],P[5]), e2=cadd(P[2],P[6]), e3=cadd(P[3],P[7]);
  float2 o0=csub(P[0],P[4]), o1=csub(P[1],P[5]), o2=csub(P[2],P[6]), o3=csub(P[3],P[7]);
  o1 = make_float2((o1.x+o1.y)*C707, (o1.y-o1.x)*C707);    // * w8^1
  o2 = make_float2(o2.y, -o2.x);                           // * w8^2 = -i
  o3 = make_float2((o3.y-o3.x)*C707, -(o3.x+o3.y)*C707);   // * w8^3
  float2 q0,q1,q2,q3;
  bf4_fwd(e0,e1,e2,e3,q0,q1,q2,q3);
  P[0]=q0; P[2]=q1; P[4]=q2; P[6]=q3;
  bf4_fwd(o0,o1,o2,o3,q0,q1,q2,q3);
  P[1]=q0; P[3]=q1; P[5]=q2; P[7]=q3;
}
__device__ __forceinline__ void inv8(float2 P[8]) {
  float2 E0,E1,E2,E3,O0,O1,O2,O3;
  bf4_inv(P[0],P[2],P[4],P[6],E0,E1,E2,E3);
  bf4_inv(P[1],P[3],P[5],P[7],O0,O1,O2,O3);
  O1 = make_float2((O1.x-O1.y)*C707, (O1.x+O1.y)*C707);
  O2 = make_float2(-O2.y, O2.x);
  O3 = make_float2(-(O3.x+O3.y)*C707, (O3.x-O3.y)*C707);
  P[0]=cadd(E0,O0); P[4]=csub(E0,O0);
  P[1]=cadd(E1,O1); P[5]=csub(E1,O1);
  P[2]=cadd(E2,O2); P[6]=csub(E2,O2);
  P[3]=cadd(E3,O3); P[7]=csub(E3,O3);
}

// Dual-buffer radix-8 stages: X0 = even-bin pipe, X1 = odd-bin pipe of the SAME
// signal; 4 independent butterflies/thread, shared twiddle loads.
template<int M>
__device__ __forceinline__ void fwd_stage8_2(float2* __restrict__ X0,
                                             float2* __restrict__ X1, int t) {
  #pragma unroll
  for (int r = 0; r < 2; ++r) {
    int s = t + NTH*r;
    int i2 = s & (M-1);
    int g  = s / M;
    int base = g*8*M + i2;
    const float2* __restrict__ wp = TWID + TWOFF<M>::v + i2*7;
    float2 w[7];
    #pragma unroll
    for (int j=0;j<7;++j) w[j] = wp[j];
    float2 Pa[8], Pb[8];
    #pragma unroll
    for (int j=0;j<8;++j) { Pa[j] = X0[PIDX(base + j*M)]; Pb[j] = X1[PIDX(base + j*M)]; }
    fwd8(Pa); fwd8(Pb);
    X0[PIDX(base)] = Pa[0];
    X1[PIDX(base)] = Pb[0];
    #pragma unroll
    for (int j=1;j<8;++j) {
      X0[PIDX(base + j*M)] = cmul(Pa[j], w[j-1]);
      X1[PIDX(base + j*M)] = cmul(Pb[j], w[j-1]);
    }
  }
}
template<int M>
__device__ __forceinline__ void inv_stage8_2(float2* __restrict__ X0,
                                             float2* __restrict__ X1, int t) {
  #pragma unroll
  for (int r = 0; r < 2; ++r) {
    int s = t + NTH*r;
    int i2 = s & (M-1);
    int g  = s / M;
    int base = g*8*M + i2;
    const float2* __restrict__ wp = TWID + TWOFF<M>::v + i2*7;
    float2 w[7];
    #pragma unroll
    for (int j=0;j<7;++j) { float2 v = wp[j]; w[j] = make_float2(v.x, -v.y); }  // conj
    float2 Pa[8], Pb[8];
    Pa[0] = X0[PIDX(base)];
    Pb[0] = X1[PIDX(base)];
    #pragma unroll
    for (int j=1;j<8;++j) {
      Pa[j] = cmul(X0[PIDX(base + j*M)], w[j-1]);
      Pb[j] = cmul(X1[PIDX(base + j*M)], w[j-1]);
    }
    inv8(Pa); inv8(Pb);
    #pragma unroll
    for (int j=0;j<8;++j) {
      X0[PIDX(base + j*M)] = Pa[j];
      X1[PIDX(base + j*M)] = Pb[j];
    }
  }
}

__device__ __forceinline__ void fft_mid_fwd2(float2* __restrict__ X0,
                                             float2* __restrict__ X1, int t) {
  __syncthreads();
  fwd_stage8_2<512>(X0,X1,t); __syncthreads();
  fwd_stage8_2<64>(X0,X1,t);  __syncthreads();
  fwd_stage8_2<8>(X0,X1,t);   __syncthreads();
}
__device__ __forceinline__ void fft_mid_inv2(float2* __restrict__ X0,
                                             float2* __restrict__ X1, int t) {
  __syncthreads();
  inv_stage8_2<8>(X0,X1,t);   __syncthreads();
  inv_stage8_2<64>(X0,X1,t);  __syncthreads();
  inv_stage8_2<512>(X0,X1,t); __syncthreads();
}

// fused final fwd (m=1) -> pointwise (X0*KA, X1*KB) -> first inv (m=1)
__device__ __forceinline__ void middle_pointwise2(float2* __restrict__ X0,
                                                  float2* __restrict__ X1,
                                                  const float2* __restrict__ KA,
                                                  const float2* __restrict__ KB, int t) {
  #pragma unroll
  for (int r = 0; r < 2; ++r) {
    int base = 8*(t + NTH*r);
    float2 ka[8], kb[8];
    #pragma unroll
    for (int q=0;q<8;++q) { ka[q] = KA[base+q]; kb[q] = KB[base+q]; }
    float2 Pa[8], Pb[8];
    #pragma unroll
    for (int q=0;q<8;++q) { Pa[q] = X0[PIDX(base+q)]; Pb[q] = X1[PIDX(base+q)]; }
    fwd8(Pa); fwd8(Pb);
    #pragma unroll
    for (int q=0;q<8;++q) { Pa[q] = cmul(Pa[q], ka[q]); Pb[q] = cmul(Pb[q], kb[q]); }
    inv8(Pa); inv8(Pb);
    #pragma unroll
    for (int q=0;q<8;++q) { X0[PIDX(base+q)] = Pa[q]; X1[PIDX(base+q)] = Pb[q]; }
  }
}

// ---------------- MLP: h3[l, 64] (unchanged) ----------------
__global__ __launch_bounds__(256) void mlp_kernel(
    const float* __restrict__ W1, const float* __restrict__ b1, const float* __restrict__ fq0,
    const float* __restrict__ W2, const float* __restrict__ b2, const float* __restrict__ fq1,
    const float* __restrict__ W3, const float* __restrict__ b3, const float* __restrict__ fq2,
    float* __restrict__ h3g) {
  __shared__ float hs[2][16][64];
  int tid = threadIdx.x;
  int lane = tid & 63, w = tid >> 6;
  int l0 = blockIdx.x * 16;

  float w1r[5];
  #pragma unroll
  for (int e = 0; e < 5; ++e) w1r[e] = W1[lane*5+e];
  float b1v = b1[lane], f0 = fq0[lane];
  #pragma unroll
  for (int r = 0; r < 4; ++r) {
    int l = l0 + w + 4*r;
    float t = (float)l * (1.0f / (float)(L_SEQ - 1));
    float ang = 6.2831853071795864769f * (float)l / (float)L_SEQ;
    float s0, c0, s1, c1;
    __sincosf(1e-4f * ang, &s0, &c0);
    __sincosf(ang, &s1, &c1);
    float acc = b1v + t*w1r[0] + c0*w1r[1] + c1*w1r[2] - s0*w1r[3] - s1*w1r[4];
    hs[0][w + 4*r][lane] = __sinf(f0 * acc);
  }
  __syncthreads();

  float wr[64];
  #pragma unroll
  for (int j = 0; j < 16; ++j) *(float4*)&wr[4*j] = *(const float4*)&W2[lane*64 + 4*j];
  float b2v = b2[lane], f1 = fq1[lane];
  #pragma unroll
  for (int r = 0; r < 4; ++r) {
    int ll = w + 4*r;
    float a0 = 0.f, a1 = 0.f, a2 = 0.f, a3 = 0.f;
    #pragma unroll
    for (int o = 0; o < 64; o += 4) {
      a0 += hs[0][ll][o+0] * wr[o+0];
      a1 += hs[0][ll][o+1] * wr[o+1];
      a2 += hs[0][ll][o+2] * wr[o+2];
      a3 += hs[0][ll][o+3] * wr[o+3];
    }
    hs[1][ll][lane] = __sinf(f1 * (b2v + ((a0+a1)+(a2+a3))));
  }
  __syncthreads();

  #pragma unroll
  for (int j = 0; j < 16; ++j) *(float4*)&wr[4*j] = *(const float4*)&W3[lane*64 + 4*j];
  float b3v = b3[lane], f2 = fq2[lane];
  #pragma unroll
  for (int r = 0; r < 4; ++r) {
    int ll = w + 4*r;
    float a0 = 0.f, a1 = 0.f, a2 = 0.f, a3 = 0.f;
    #pragma unroll
    for (int o = 0; o < 64; o += 4) {
      a0 += hs[1][ll][o+0] * wr[o+0];
      a1 += hs[1][ll][o+1] * wr[o+1];
      a2 += hs[1][ll][o+2] * wr[o+2];
      a3 += hs[1][ll][o+3] * wr[o+3];
    }
    h3g[(size_t)(l0 + ll) * 64 + lane] = __sinf(f2 * (b3v + ((a0+a1)+(a2+a3))));
  }
}

// ---------------- kwrite (unchanged) ----------------
__global__ __launch_bounds__(256) void kwrite_kernel(const float* __restrict__ h3g,
                                                     const float* __restrict__ Wout,
                                                     const float* __restrict__ Dv,
                                                     float* __restrict__ kbuf) {
  __shared__ float tileh[256][65];
  int tid = threadIdx.x;
  int l0 = blockIdx.x * 256;
  int c0 = blockIdx.y * 32;
  {
    const float4* src = (const float4*)(h3g + (size_t)l0 * 64);
    #pragma unroll
    for (int q = 0; q < 16; ++q) {
      int idx = tid + 256*q;
      int row = idx >> 4, col4 = idx & 15;
      float4 v = src[idx];
      tileh[row][col4*4+0] = v.x;
      tileh[row][col4*4+1] = v.y;
      tileh[row][col4*4+2] = v.z;
      tileh[row][col4*4+3] = v.w;
    }
  }
  __syncthreads();
  float hr[64];
  #pragma unroll
  for (int o = 0; o < 64; ++o) hr[o] = tileh[tid][o];
  int l = l0 + tid;
  float t = (float)l * (1.0f / (float)(L_SEQ - 1));
  const float mind = -3.0701134573253945f;
  const float maxd = -15.350567286626972f;
  for (int jj = 0; jj < 32; ++jj) {
    int c = c0 + jj;
    float a0 = 0.f, a1 = 0.f, a2 = 0.f, a3 = 0.f;
    #pragma unroll
    for (int o = 0; o < 64; o += 4) {
      a0 += hr[o+0] * Wout[c*64+o+0];
      a1 += hr[o+1] * Wout[c*64+o+1];
      a2 += hr[o+2] * Wout[c*64+o+2];
      a3 += hr[o+3] * Wout[c*64+o+3];
    }
    float acc = (a0+a1)+(a2+a3);
    float delta = mind + (maxd - mind) * ((float)c * (1.0f/255.0f));
    float dec = __expf(-t * fabsf(delta)) + 0.05f;
    float v = acc * dec;
    if (l == 0) v += Dv[c];
    kbuf[(size_t)c * L_SEQ + l] = v;
  }
}

// ---------------- kernel spectra: BOTH pipes per block (unchanged R17) ----------------
__global__ __launch_bounds__(NTH) void kf_kernel(const float* __restrict__ kbuf,
                                                 float2* __restrict__ Kf) {
  __shared__ float2 X0[LDS_SZ];
  __shared__ float2 X1[LDS_SZ];
  int c = blockIdx.x;
  int t = threadIdx.x;
  const float* kr = kbuf + (size_t)c * L_SEQ;
  const float sc = 1.0f / 16384.0f;
  #pragma unroll
  for (int r = 0; r < 2; ++r) {
    int n0 = 4*t + 2048*r;
    float4 lo4 = *(const float4*)(kr + n0);
    float4 hi4 = *(const float4*)(kr + n0 + 4096);
    float s16, c16; __sincosf(-ANG16 * (float)n0, &s16, &c16);
    float2 w16 = make_float2(c16, s16);
    #pragma unroll
    for (int j = 0; j < 4; ++j) {
      if (j) w16 = cmul(w16, make_float2(CS16, -SN16));
      float2 w8 = cmul(w16, w16);
      float klo = ((const float*)&lo4)[j];
      float khi = ((const float*)&hi4)[j];
      // pipe 0 (even bins)
      X0[PIDX(n0+j)]      = make_float2(klo + khi, 0.f);
      float d = klo - khi;
      X0[PIDX(n0+j+4096)] = make_float2(d * w8.x, d * w8.y);
      // pipe 1 (odd bins): pre-twiddle w16384^n
      float2 vlo = make_float2(klo * w16.x, klo * w16.y);
      float2 vhi = make_float2(khi * w16.y, -khi * w16.x);
      X1[PIDX(n0+j)]      = cadd(vlo, vhi);
      X1[PIDX(n0+j+4096)] = cmul(csub(vlo, vhi), w8);
    }
  }
  fft_mid_fwd2(X0, X1, t);
  #pragma unroll
  for (int r = 0; r < 2; ++r) {
    int base = 8*(t + NTH*r);
    float2 P0[8], P1[8];
    #pragma unroll
    for (int q=0;q<8;++q) { P0[q] = X0[PIDX(base+q)]; P1[q] = X1[PIDX(base+q)]; }
    fwd8(P0); fwd8(P1);
    float2* out0 = Kf + (size_t)c * 16384 + base;
    float2* out1 = out0 + 8192;
    #pragma unroll
    for (int q=0;q<8;++q) {
      out0[q] = make_float2(P0[q].x*sc, P0[q].y*sc);
      out1[q] = make_float2(P1[q].x*sc, P1[q].y*sc);
    }
  }
}

// ---------------- conv: p-loop inside block + register prefetch of next round's x ----------------
// grid (256 channels); one block does all 4 batch-pairs, prefetch hides HBM latency.
__global__ __launch_bounds__(NTH) void conv_kernel(const float* __restrict__ x,
                                                   const float2* __restrict__ Kf,
                                                   float* __restrict__ y) {
  __shared__ float2 X0[LDS_SZ];
  __shared__ float2 X1[LDS_SZ];
  int c = blockIdx.x;
  int t = threadIdx.x;
  const float2* KA = Kf + (size_t)c * 16384;
  const float2* KB = KA + 8192;

  // initial load (p=0)
  float4 pf[2][4];
  {
    const float* u0 = x + ((size_t)0 * HID + c) * L_SEQ;
    const float* u1 = x + ((size_t)4 * HID + c) * L_SEQ;
    #pragma unroll
    for (int r = 0; r < 2; ++r) {
      int n0 = 4*t + 2048*r;
      pf[r][0] = *(const float4*)(u0 + n0);
      pf[r][1] = *(const float4*)(u1 + n0);
      pf[r][2] = *(const float4*)(u0 + n0 + 4096);
      pf[r][3] = *(const float4*)(u1 + n0 + 4096);
    }
  }

  for (int p = 0; p < 4; ++p) {
    __syncthreads();   // previous epilog's X reads complete before prolog writes
    // prolog: consume pf, feed both pipes (w8 = w16^2, shared sincos chain)
    #pragma unroll
    for (int r = 0; r < 2; ++r) {
      int n0 = 4*t + 2048*r;
      float sb, cb; __sincosf(-ANG16 * (float)n0, &sb, &cb);
      float2 w16 = make_float2(cb, sb);
      #pragma unroll
      for (int j = 0; j < 4; ++j) {
        if (j) w16 = cmul(w16, make_float2(CS16, -SN16));
        float2 w8 = cmul(w16, w16);
        float2 vlo = make_float2(((const float*)&pf[r][0])[j], ((const float*)&pf[r][1])[j]);
        float2 vhi = make_float2(((const float*)&pf[r][2])[j], ((const float*)&pf[r][3])[j]);
        // pipe A (even bins)
        X0[PIDX(n0+j)]      = cadd(vlo, vhi);
        X0[PIDX(n0+j+4096)] = cmul(csub(vlo, vhi), w8);
        // pipe B (odd bins): pre-twiddle
        float2 vloB = cmul(vlo, w16);
        float2 vhiB = cmul(vhi, make_float2(w16.y, -w16.x));   // * w16 * (-i)
        X1[PIDX(n0+j)]      = cadd(vloB, vhiB);
        X1[PIDX(n0+j+4096)] = cmul(csub(vloB, vhiB), w8);
      }
    }
    fft_mid_fwd2(X0, X1, t);
    middle_pointwise2(X0, X1, KA, KB, t);
    // prefetch next round's x (pf dead after prolog; loads fly over the inv stages)
    if (p < 3) {
      const float* u0n = x + ((size_t)(p + 1) * HID + c) * L_SEQ;
      const float* u1n = x + ((size_t)(p + 5) * HID + c) * L_SEQ;
      #pragma unroll
      for (int r = 0; r < 2; ++r) {
        int n0 = 4*t + 2048*r;
        pf[r][0] = *(const float4*)(u0n + n0);
        pf[r][1] = *(const float4*)(u1n + n0);
        pf[r][2] = *(const float4*)(u0n + n0 + 4096);
        pf[r][3] = *(const float4*)(u1n + n0 + 4096);
      }
    }
    fft_mid_inv2(X0, X1, t);
    // epilog: combine both pipes (w8b = w16b^2), store y for this p
    float* y0 = y + ((size_t)p       * HID + c) * L_SEQ;
    float* y1 = y + ((size_t)(p + 4) * HID + c) * L_SEQ;
    #pragma unroll
    for (int r = 0; r < 2; ++r) {
      int n0 = 4*t + 2048*r;
      float sb, cb; __sincosf(ANG16 * (float)n0, &sb, &cb);
      float2 w16b = make_float2(cb, sb);
      float4 w00, w01, w10, w11;
      #pragma unroll
      for (int j = 0; j < 4; ++j) {
        if (j) w16b = cmul(w16b, make_float2(CS16, SN16));
        float2 w8b = cmul(w16b, w16b);
        float2 P0 = X0[PIDX(n0+j)], Q0 = X0[PIDX(n0+j+4096)];
        float2 P1 = X1[PIDX(n0+j)], Q1 = X1[PIDX(n0+j+4096)];
        float2 tt0 = cmul(Q0, w8b);
        float2 tt1 = cmul(Q1, w8b);
        float2 lo = cadd(cadd(P0, tt0), cmul(cadd(P1, tt1), w16b));
        float2 hi = cadd(csub(P0, tt0), cmul(csub(P1, tt1), make_float2(-w16b.y, w16b.x)));
        ((float*)&w00)[j] = lo.x; ((float*)&w01)[j] = lo.y;
        ((float*)&w10)[j] = hi.x; ((float*)&w11)[j] = hi.y;
      }
      *(float4*)(y0 + n0)        = w00;
      *(float4*)(y1 + n0)        = w01;
      *(float4*)(y0 + n0 + 4096) = w10;
      *(float4*)(y1 + n0 + 4096) = w11;
    }
  }
}

extern "C" void kernel_launch(void* const* d_in, const int* in_sizes, int n_in,
                              void* d_out, int out_size, void* d_ws, size_t ws_size,
                              hipStream_t stream) {
  const float* x    = (const float*)d_in[0];
  const float* W1   = (const float*)d_in[1];
  const float* b1   = (const float*)d_in[2];
  const float* fq0  = (const float*)d_in[3];
  const float* W2   = (const float*)d_in[4];
  const float* b2   = (const float*)d_in[5];
  const float* fq1  = (const float*)d_in[6];
  const float* W3   = (const float*)d_in[7];
  const float* b3   = (const float*)d_in[8];
  const float* fq2  = (const float*)d_in[9];
  const float* Wout = (const float*)d_in[10];
  const float* Dv   = (const float*)d_in[11];

  // ws: [0,8)MB kbuf ; [8,40)MB Kf. h3 (2MB) aliases Kf tail: mlp->kwrite->kf stream-ordered.
  float*  kbuf = (float*)d_ws;
  float2* Kf   = (float2*)((char*)d_ws + (size_t)HID * L_SEQ * sizeof(float));
  float*  h3g  = (float*)((char*)d_ws + 38ull*1024*1024);
  float*  y    = (float*)d_out;

  twid_kernel  <<<dim3(16),    256, 0, stream>>>();
  mlp_kernel   <<<dim3(512),   256, 0, stream>>>(W1,b1,fq0,W2,b2,fq1,W3,b3,fq2,h3g);
  kwrite_kernel<<<dim3(32, 8), 256, 0, stream>>>(h3g, Wout, Dv, kbuf);
  kf_kernel    <<<dim3(256),    NTH, 0, stream>>>(kbuf, Kf);
  conv_kernel  <<<dim3(256),    NTH, 0, stream>>>(x, Kf, y);
}

// Round 19
// 140.941 us; speedup vs baseline: 1.5218x; 1.5218x over previous
//
#include <hip/hip_runtime.h>

#define L_SEQ 8192
#define NTH 1024
#define HID 256
#define PIDX(i) ((i) + ((i) >> 4))
#define LDS_SZ 8704        // PIDX(8191)=8702 -> 69632 B per buffer

#define ANG16 3.83495196971410315e-4f   // 2*pi/16384
#define CS16 0.99999992646571789f       // cos(2*pi/16384)
#define SN16 3.83495187571395563e-4f    // sin(2*pi/16384)
#define C707 0.70710678118654752f

// Twiddle table (R14, verified): TWID[off(M)+i2*7+j-1] = exp(-2pi*i*i2*j/(8M))
__device__ float2 TWID[4088];
template<int M> struct TWOFF;
template<> struct TWOFF<512> { static constexpr int v = 0;    };
template<> struct TWOFF<64>  { static constexpr int v = 3584; };
template<> struct TWOFF<8>   { static constexpr int v = 4032; };

__global__ __launch_bounds__(256) void twid_kernel() {
  int g = blockIdx.x * 256 + threadIdx.x;
  float denom;
  int h;
  if (g < 3584)      { h = g;        denom = 4096.0f; }
  else if (g < 4032) { h = g - 3584; denom = 512.0f;  }
  else if (g < 4088) { h = g - 4032; denom = 64.0f;   }
  else return;
  int i = h / 7, j = h - 7*i + 1;
  float s, c;
  sincosf(-6.2831853071795864769f * (float)(i*j) / denom, &s, &c);
  TWID[g] = make_float2(c, s);
}

__device__ __forceinline__ float2 cmul(float2 a, float2 b) {
  return make_float2(a.x*b.x - a.y*b.y, a.x*b.y + a.y*b.x);
}
__device__ __forceinline__ float2 cadd(float2 a, float2 b){ return make_float2(a.x+b.x, a.y+b.y); }
__device__ __forceinline__ float2 csub(float2 a, float2 b){ return make_float2(a.x-b.x, a.y-b.y); }

__device__ __forceinline__ void bf4_fwd(float2 a0, float2 a1, float2 a2, float2 a3,
                                        float2& o0, float2& o1, float2& o2, float2& o3) {
  float2 t0 = cadd(a0,a2), t1 = csub(a0,a2), t2 = cadd(a1,a3), t3 = csub(a1,a3);
  o0 = cadd(t0,t2);
  o2 = csub(t0,t2);
  o1 = make_float2(t1.x + t3.y, t1.y - t3.x);   // t1 - i*t3
  o3 = make_float2(t1.x - t3.y, t1.y + t3.x);   // t1 + i*t3
}
__device__ __forceinline__ void bf4_inv(float2 c0, float2 c1, float2 c2, float2 c3,
                                        float2& o0, float2& o1, float2& o2, float2& o3) {
  float2 u0 = cadd(c0,c2), u2 = csub(c0,c2), u1 = cadd(c1,c3);
  float2 v3 = make_float2(c3.y - c1.y, c1.x - c3.x);  // i*(c1-c3)
  o0 = cadd(u0,u1); o2 = csub(u0,u1); o1 = cadd(u2,v3); o3 = csub(u2,v3);
}

// 8-point DIF DFT in registers, natural output order (verified R7-R18)
__device__ __forceinline__ void fwd8(float2 P[8]) {
  float2 e0=cadd(P[0],P[4]), e1=cadd(P[1],P[5]), e2=cadd(P[2],P[6]), e3=cadd(P[3],P[7]);
  float2 o0=csub(P[0],P[4]), o1=csub(P[1],P[5]), o2=csub(P[2],P[6]), o3=csub(P[3],P[7]);
  o1 = make_float2((o1.x+o1.y)*C707, (o1.y-o1.x)*C707);    // * w8^1
  o2 = make_float2(o2.y, -o2.x);                           // * w8^2 = -i
  o3 = make_float2((o3.y-o3.x)*C707, -(o3.x+o3.y)*C707);   // * w8^3
  float2 q0,q1,q2,q3;
  bf4_fwd(e0,e1,e2,e3,q0,q1,q2,q3);
  P[0]=q0; P[2]=q1; P[4]=q2; P[6]=q3;
  bf4_fwd(o0,o1,o2,o3,q0,q1,q2,q3);
  P[1]=q0; P[3]=q1; P[5]=q2; P[7]=q3;
}
__device__ __forceinline__ void inv8(float2 P[8]) {
  float2 E0,E1,E2,E3,O0,O1,O2,O3;
  bf4_inv(P[0],P[2],P[4],P[6],E0,E1,E2,E3);
  bf4_inv(P[1],P[3],P[5],P[7],O0,O1,O2,O3);
  O1 = make_float2((O1.x-O1.y)*C707, (O1.x+O1.y)*C707);
  O2 = make_float2(-O2.y, O2.x);
  O3 = make_float2(-(O3.x+O3.y)*C707, (O3.x-O3.y)*C707);
  P[0]=cadd(E0,O0); P[4]=csub(E0,O0);
  P[1]=cadd(E1,O1); P[5]=csub(E1,O1);
  P[2]=cadd(E2,O2); P[6]=csub(E2,O2);
  P[3]=cadd(E3,O3); P[7]=csub(E3,O3);
}

// 1024-thread stages: exactly 1 butterfly per thread per pipe; pipes processed
// SEQUENTIALLY to cap live registers (~50) so the 1024-thread allocator's
// 64-VGPR target fits without spill. Twiddles loaded once, used for both pipes.
template<int M>
__device__ __forceinline__ void fwd_stage8_2(float2* __restrict__ X0,
                                             float2* __restrict__ X1, int t) {
  int i2 = t & (M-1);
  int g  = t / M;
  int base = g*8*M + i2;
  const float2* __restrict__ wp = TWID + TWOFF<M>::v + i2*7;
  float2 w[7];
  #pragma unroll
  for (int j=0;j<7;++j) w[j] = wp[j];
  {
    float2 P[8];
    #pragma unroll
    for (int j=0;j<8;++j) P[j] = X0[PIDX(base + j*M)];
    fwd8(P);
    X0[PIDX(base)] = P[0];
    #pragma unroll
    for (int j=1;j<8;++j) X0[PIDX(base + j*M)] = cmul(P[j], w[j-1]);
  }
  {
    float2 P[8];
    #pragma unroll
    for (int j=0;j<8;++j) P[j] = X1[PIDX(base + j*M)];
    fwd8(P);
    X1[PIDX(base)] = P[0];
    #pragma unroll
    for (int j=1;j<8;++j) X1[PIDX(base + j*M)] = cmul(P[j], w[j-1]);
  }
}
template<int M>
__device__ __forceinline__ void inv_stage8_2(float2* __restrict__ X0,
                                             float2* __restrict__ X1, int t) {
  int i2 = t & (M-1);
  int g  = t / M;
  int base = g*8*M + i2;
  const float2* __restrict__ wp = TWID + TWOFF<M>::v + i2*7;
  float2 w[7];
  #pragma unroll
  for (int j=0;j<7;++j) { float2 v = wp[j]; w[j] = make_float2(v.x, -v.y); }  // conj
  {
    float2 P[8];
    P[0] = X0[PIDX(base)];
    #pragma unroll
    for (int j=1;j<8;++j) P[j] = cmul(X0[PIDX(base + j*M)], w[j-1]);
    inv8(P);
    #pragma unroll
    for (int j=0;j<8;++j) X0[PIDX(base + j*M)] = P[j];
  }
  {
    float2 P[8];
    P[0] = X1[PIDX(base)];
    #pragma unroll
    for (int j=1;j<8;++j) P[j] = cmul(X1[PIDX(base + j*M)], w[j-1]);
    inv8(P);
    #pragma unroll
    for (int j=0;j<8;++j) X1[PIDX(base + j*M)] = P[j];
  }
}

__device__ __forceinline__ void fft_mid_fwd2(float2* __restrict__ X0,
                                             float2* __restrict__ X1, int t) {
  __syncthreads();
  fwd_stage8_2<512>(X0,X1,t); __syncthreads();
  fwd_stage8_2<64>(X0,X1,t);  __syncthreads();
  fwd_stage8_2<8>(X0,X1,t);   __syncthreads();
}
__device__ __forceinline__ void fft_mid_inv2(float2* __restrict__ X0,
                                             float2* __restrict__ X1, int t) {
  __syncthreads();
  inv_stage8_2<8>(X0,X1,t);   __syncthreads();
  inv_stage8_2<64>(X0,X1,t);  __syncthreads();
  inv_stage8_2<512>(X0,X1,t); __syncthreads();
}

// fused final fwd (m=1) -> pointwise (X0*KA, X1*KB) -> first inv (m=1); sequential pipes
__device__ __forceinline__ void middle_pointwise2(float2* __restrict__ X0,
                                                  float2* __restrict__ X1,
                                                  const float2* __restrict__ KA,
                                                  const float2* __restrict__ KB, int t) {
  int base = 8*t;
  {
    float2 k[8];
    #pragma unroll
    for (int q=0;q<8;++q) k[q] = KA[base+q];
    float2 P[8];
    #pragma unroll
    for (int q=0;q<8;++q) P[q] = X0[PIDX(base+q)];
    fwd8(P);
    #pragma unroll
    for (int q=0;q<8;++q) P[q] = cmul(P[q], k[q]);
    inv8(P);
    #pragma unroll
    for (int q=0;q<8;++q) X0[PIDX(base+q)] = P[q];
  }
  {
    float2 k[8];
    #pragma unroll
    for (int q=0;q<8;++q) k[q] = KB[base+q];
    float2 P[8];
    #pragma unroll
    for (int q=0;q<8;++q) P[q] = X1[PIDX(base+q)];
    fwd8(P);
    #pragma unroll
    for (int q=0;q<8;++q) P[q] = cmul(P[q], k[q]);
    inv8(P);
    #pragma unroll
    for (int q=0;q<8;++q) X1[PIDX(base+q)] = P[q];
  }
}

// ---------------- MLP: h3[l, 64] (unchanged) ----------------
__global__ __launch_bounds__(256) void mlp_kernel(
    const float* __restrict__ W1, const float* __restrict__ b1, const float* __restrict__ fq0,
    const float* __restrict__ W2, const float* __restrict__ b2, const float* __restrict__ fq1,
    const float* __restrict__ W3, const float* __restrict__ b3, const float* __restrict__ fq2,
    float* __restrict__ h3g) {
  __shared__ float hs[2][16][64];
  int tid = threadIdx.x;
  int lane = tid & 63, w = tid >> 6;
  int l0 = blockIdx.x * 16;

  float w1r[5];
  #pragma unroll
  for (int e = 0; e < 5; ++e) w1r[e] = W1[lane*5+e];
  float b1v = b1[lane], f0 = fq0[lane];
  #pragma unroll
  for (int r = 0; r < 4; ++r) {
    int l = l0 + w + 4*r;
    float t = (float)l * (1.0f / (float)(L_SEQ - 1));
    float ang = 6.2831853071795864769f * (float)l / (float)L_SEQ;
    float s0, c0, s1, c1;
    __sincosf(1e-4f * ang, &s0, &c0);
    __sincosf(ang, &s1, &c1);
    float acc = b1v + t*w1r[0] + c0*w1r[1] + c1*w1r[2] - s0*w1r[3] - s1*w1r[4];
    hs[0][w + 4*r][lane] = __sinf(f0 * acc);
  }
  __syncthreads();

  float wr[64];
  #pragma unroll
  for (int j = 0; j < 16; ++j) *(float4*)&wr[4*j] = *(const float4*)&W2[lane*64 + 4*j];
  float b2v = b2[lane], f1 = fq1[lane];
  #pragma unroll
  for (int r = 0; r < 4; ++r) {
    int ll = w + 4*r;
    float a0 = 0.f, a1 = 0.f, a2 = 0.f, a3 = 0.f;
    #pragma unroll
    for (int o = 0; o < 64; o += 4) {
      a0 += hs[0][ll][o+0] * wr[o+0];
      a1 += hs[0][ll][o+1] * wr[o+1];
      a2 += hs[0][ll][o+2] * wr[o+2];
      a3 += hs[0][ll][o+3] * wr[o+3];
    }
    hs[1][ll][lane] = __sinf(f1 * (b2v + ((a0+a1)+(a2+a3))));
  }
  __syncthreads();

  #pragma unroll
  for (int j = 0; j < 16; ++j) *(float4*)&wr[4*j] = *(const float4*)&W3[lane*64 + 4*j];
  float b3v = b3[lane], f2 = fq2[lane];
  #pragma unroll
  for (int r = 0; r < 4; ++r) {
    int ll = w + 4*r;
    float a0 = 0.f, a1 = 0.f, a2 = 0.f, a3 = 0.f;
    #pragma unroll
    for (int o = 0; o < 64; o += 4) {
      a0 += hs[1][ll][o+0] * wr[o+0];
      a1 += hs[1][ll][o+1] * wr[o+1];
      a2 += hs[1][ll][o+2] * wr[o+2];
      a3 += hs[1][ll][o+3] * wr[o+3];
    }
    h3g[(size_t)(l0 + ll) * 64 + lane] = __sinf(f2 * (b3v + ((a0+a1)+(a2+a3))));
  }
}

// ---------------- kwrite (unchanged) ----------------
__global__ __launch_bounds__(256) void kwrite_kernel(const float* __restrict__ h3g,
                                                     const float* __restrict__ Wout,
                                                     const float* __restrict__ Dv,
                                                     float* __restrict__ kbuf) {
  __shared__ float tileh[256][65];
  int tid = threadIdx.x;
  int l0 = blockIdx.x * 256;
  int c0 = blockIdx.y * 32;
  {
    const float4* src = (const float4*)(h3g + (size_t)l0 * 64);
    #pragma unroll
    for (int q = 0; q < 16; ++q) {
      int idx = tid + 256*q;
      int row = idx >> 4, col4 = idx & 15;
      float4 v = src[idx];
      tileh[row][col4*4+0] = v.x;
      tileh[row][col4*4+1] = v.y;
      tileh[row][col4*4+2] = v.z;
      tileh[row][col4*4+3] = v.w;
    }
  }
  __syncthreads();
  float hr[64];
  #pragma unroll
  for (int o = 0; o < 64; ++o) hr[o] = tileh[tid][o];
  int l = l0 + tid;
  float t = (float)l * (1.0f / (float)(L_SEQ - 1));
  const float mind = -3.0701134573253945f;
  const float maxd = -15.350567286626972f;
  for (int jj = 0; jj < 32; ++jj) {
    int c = c0 + jj;
    float a0 = 0.f, a1 = 0.f, a2 = 0.f, a3 = 0.f;
    #pragma unroll
    for (int o = 0; o < 64; o += 4) {
      a0 += hr[o+0] * Wout[c*64+o+0];
      a1 += hr[o+1] * Wout[c*64+o+1];
      a2 += hr[o+2] * Wout[c*64+o+2];
      a3 += hr[o+3] * Wout[c*64+o+3];
    }
    float acc = (a0+a1)+(a2+a3);
    float delta = mind + (maxd - mind) * ((float)c * (1.0f/255.0f));
    float dec = __expf(-t * fabsf(delta)) + 0.05f;
    float v = acc * dec;
    if (l == 0) v += Dv[c];
    kbuf[(size_t)c * L_SEQ + l] = v;
  }
}

// ---------------- kernel spectra: 1024 threads, both pipes, sequential stages ----------------
__global__ __launch_bounds__(NTH) void kf_kernel(const float* __restrict__ kbuf,
                                                 float2* __restrict__ Kf) {
  __shared__ float2 X0[LDS_SZ];
  __shared__ float2 X1[LDS_SZ];
  int c = blockIdx.x;
  int t = threadIdx.x;
  const float* kr = kbuf + (size_t)c * L_SEQ;
  const float sc = 1.0f / 16384.0f;
  {
    int n0 = 4*t;
    float4 lo4 = *(const float4*)(kr + n0);
    float4 hi4 = *(const float4*)(kr + n0 + 4096);
    float s16, c16; __sincosf(-ANG16 * (float)n0, &s16, &c16);
    float2 w16 = make_float2(c16, s16);
    #pragma unroll
    for (int j = 0; j < 4; ++j) {
      if (j) w16 = cmul(w16, make_float2(CS16, -SN16));
      float2 w8 = cmul(w16, w16);
      float klo = ((const float*)&lo4)[j];
      float khi = ((const float*)&hi4)[j];
      // pipe 0 (even bins)
      X0[PIDX(n0+j)]      = make_float2(klo + khi, 0.f);
      float d = klo - khi;
      X0[PIDX(n0+j+4096)] = make_float2(d * w8.x, d * w8.y);
      // pipe 1 (odd bins): pre-twiddle w16384^n
      float2 vlo = make_float2(klo * w16.x, klo * w16.y);
      float2 vhi = make_float2(khi * w16.y, -khi * w16.x);
      X1[PIDX(n0+j)]      = cadd(vlo, vhi);
      X1[PIDX(n0+j+4096)] = cmul(csub(vlo, vhi), w8);
    }
  }
  fft_mid_fwd2(X0, X1, t);
  {
    int base = 8*t;
    float2* out0 = Kf + (size_t)c * 16384 + base;
    float2* out1 = out0 + 8192;
    {
      float2 P[8];
      #pragma unroll
      for (int q=0;q<8;++q) P[q] = X0[PIDX(base+q)];
      fwd8(P);
      #pragma unroll
      for (int q=0;q<8;++q) out0[q] = make_float2(P[q].x*sc, P[q].y*sc);
    }
    {
      float2 P[8];
      #pragma unroll
      for (int q=0;q<8;++q) P[q] = X1[PIDX(base+q)];
      fwd8(P);
      #pragma unroll
      for (int q=0;q<8;++q) out1[q] = make_float2(P[q].x*sc, P[q].y*sc);
    }
  }
}

// ---------------- conv: 1024 threads, both pipes concurrently, sequential stages ----------------
// grid (256 channels, 4 batch-pairs); 16 waves/CU (4/SIMD) at the same 139KB LDS.
__global__ __launch_bounds__(NTH) void conv_kernel(const float* __restrict__ x,
                                                   const float2* __restrict__ Kf,
                                                   float* __restrict__ y) {
  __shared__ float2 X0[LDS_SZ];
  __shared__ float2 X1[LDS_SZ];
  int c = blockIdx.x;
  int p = blockIdx.y;
  int t = threadIdx.x;
  const float* u0 = x + ((size_t)p       * HID + c) * L_SEQ;
  const float* u1 = x + ((size_t)(p + 4) * HID + c) * L_SEQ;
  const float2* KA = Kf + (size_t)c * 16384;
  const float2* KB = KA + 8192;
  float* y0 = y + ((size_t)p       * HID + c) * L_SEQ;
  float* y1 = y + ((size_t)(p + 4) * HID + c) * L_SEQ;

  // prolog: single load feeds both pipes (w8 = w16^2, shared sincos chain)
  {
    int n0 = 4*t;
    float4 a0 = *(const float4*)(u0 + n0);
    float4 a1 = *(const float4*)(u1 + n0);
    float4 b0 = *(const float4*)(u0 + n0 + 4096);
    float4 b1 = *(const float4*)(u1 + n0 + 4096);
    float sb, cb; __sincosf(-ANG16 * (float)n0, &sb, &cb);
    float2 w16 = make_float2(cb, sb);
    #pragma unroll
    for (int j = 0; j < 4; ++j) {
      if (j) w16 = cmul(w16, make_float2(CS16, -SN16));
      float2 w8 = cmul(w16, w16);
      float2 vlo = make_float2(((const float*)&a0)[j], ((const float*)&a1)[j]);
      float2 vhi = make_float2(((const float*)&b0)[j], ((const float*)&b1)[j]);
      // pipe A (even bins)
      X0[PIDX(n0+j)]      = cadd(vlo, vhi);
      X0[PIDX(n0+j+4096)] = cmul(csub(vlo, vhi), w8);
      // pipe B (odd bins): pre-twiddle
      float2 vloB = cmul(vlo, w16);
      float2 vhiB = cmul(vhi, make_float2(w16.y, -w16.x));   // * w16 * (-i)
      X1[PIDX(n0+j)]      = cadd(vloB, vhiB);
      X1[PIDX(n0+j+4096)] = cmul(csub(vloB, vhiB), w8);
    }
  }
  fft_mid_fwd2(X0, X1, t);
  middle_pointwise2(X0, X1, KA, KB, t);
  fft_mid_inv2(X0, X1, t);
  // epilog: combine both pipes directly (w8b = w16b^2, shared chain), store y
  {
    int n0 = 4*t;
    float sb, cb; __sincosf(ANG16 * (float)n0, &sb, &cb);
    float2 w16b = make_float2(cb, sb);
    float4 w00, w01, w10, w11;
    #pragma unroll
    for (int j = 0; j < 4; ++j) {
      if (j) w16b = cmul(w16b, make_float2(CS16, SN16));
      float2 w8b = cmul(w16b, w16b);
      float2 P0 = X0[PIDX(n0+j)], Q0 = X0[PIDX(n0+j+4096)];
      float2 P1 = X1[PIDX(n0+j)], Q1 = X1[PIDX(n0+j+4096)];
      float2 tt0 = cmul(Q0, w8b);
      float2 tt1 = cmul(Q1, w8b);
      float2 lo = cadd(cadd(P0, tt0), cmul(cadd(P1, tt1), w16b));
      float2 hi = cadd(csub(P0, tt0), cmul(csub(P1, tt1), make_float2(-w16b.y, w16b.x)));
      ((float*)&w00)[j] = lo.x; ((float*)&w01)[j] = lo.y;
      ((float*)&w10)[j] = hi.x; ((float*)&w11)[j] = hi.y;
    }
    *(float4*)(y0 + n0)        = w00;
    *(float4*)(y1 + n0)        = w01;
    *(float4*)(y0 + n0 + 4096) = w10;
    *(float4*)(y1 + n0 + 4096) = w11;
  }
}

extern "C" void kernel_launch(void* const* d_in, const int* in_sizes, int n_in,
                              void* d_out, int out_size, void* d_ws, size_t ws_size,
                              hipStream_t stream) {
  const float* x    = (const float*)d_in[0];
  const float* W1   = (const float*)d_in[1];
  const float* b1   = (const float*)d_in[2];
  const float* fq0  = (const float*)d_in[3];
  const float* W2   = (const float*)d_in[4];
  const float* b2   = (const float*)d_in[5];
  const float* fq1  = (const float*)d_in[6];
  const float* W3   = (const float*)d_in[7];
  const float* b3   = (const float*)d_in[8];
  const float* fq2  = (const float*)d_in[9];
  const float* Wout = (const float*)d_in[10];
  const float* Dv   = (const float*)d_in[11];

  // ws: [0,8)MB kbuf ; [8,40)MB Kf. h3 (2MB) aliases Kf tail: mlp->kwrite->kf stream-ordered.
  float*  kbuf = (float*)d_ws;
  float2* Kf   = (float2*)((char*)d_ws + (size_t)HID * L_SEQ * sizeof(float));
  float*  h3g  = (float*)((char*)d_ws + 38ull*1024*1024);
  float*  y    = (float*)d_out;

  twid_kernel  <<<dim3(16),    256, 0, stream>>>();
  mlp_kernel   <<<dim3(512),   256, 0, stream>>>(W1,b1,fq0,W2,b2,fq1,W3,b3,fq2,h3g);
  kwrite_kernel<<<dim3(32, 8), 256, 0, stream>>>(h3g, Wout, Dv, kbuf);
  kf_kernel    <<<dim3(256),    NTH, 0, stream>>>(kbuf, Kf);
  conv_kernel  <<<dim3(256, 4), NTH, 0, stream>>>(x, Kf, y);
}